// Round 8
// baseline (154.427 us; speedup 1.0000x reference)
//
#include <hip/hip_runtime.h>

#define F 64
#define H 64
#define NT 256
#define TILE_ROWS 256     // per block per iteration: 4 waves x 64 rows
#define ITERS 4
#define ROWS_PER_BLOCK (TILE_ROWS * ITERS)   // 1024
#define WPAD 72   // LDS row stride in bf16 elems (144 B): 2-way bank alias on b64 reads (free)

#define LOG2E 1.44269504088896340736f
#define LN2   0.69314718055994530942f

typedef __bf16 bf16;
typedef __attribute__((ext_vector_type(8))) __bf16 bf16x8;
typedef __attribute__((ext_vector_type(4))) short s16x4;   // v4i16: one 16x16x16 bf16 A/B frag
typedef __attribute__((ext_vector_type(4))) float f32x4;
typedef __attribute__((ext_vector_type(2))) float f32x2;

// LOG2-DOMAIN CELU (R6, verified): activations carry a log2(e) scale end-to-end.
//   y = log2e * x ;  z = log2e * celu(x) = med3(y, log2e*exp2(y) - log2e, 0)
// MUST use raw __builtin_amdgcn_exp2f (bare v_exp_f32): the std __builtin_exp2f
// emits a denormal-range fixup (+40% VALU, R5 regression). Raw exp2's
// flush-to-zero for y<-126 is exactly right here (em -> -log2e -> output -1).
// Scale bookkeeping: w_in,b_in,b_hid pre-scaled by log2e at staging; hidden W
// UNCHANGED (scale passes through: W*(z*ln2)*log2e = W*z); w_out by ln2.
// R8: the em fma runs on PAIRS via __builtin_elementwise_fma(f32x2) -> the
// backend can select v_pk_fma_f32 (VOP3P, 2 lanes/instr). If it declines it
// emits 2 scalar v_fma -> exactly the R6 stream (safe floor, no inline asm).

__device__ __forceinline__ short bfb(float v) {
    bf16 h = (bf16)v;
    return __builtin_bit_cast(short, h);
}

// post-layer activation: log2-domain celu on the 4 accum lanes, pack to a v4i16
// bf16 frag. KEY INVARIANT: for v_mfma_f32_16x16x16_bf16 the D layout
// (col=lane&15, row=(lane>>4)*4+j) is IDENTICAL to the B layout, so this frag
// is directly the next layer's B operand (kf = current m). No LDS round-trip.
__device__ __forceinline__ s16x4 celu_frag(f32x4 a) {
    const f32x2 L2  = {  LOG2E,  LOG2E };
    const f32x2 nL2 = { -LOG2E, -LOG2E };
    f32x2 e01 = { __builtin_amdgcn_exp2f(a[0]), __builtin_amdgcn_exp2f(a[1]) };
    f32x2 e23 = { __builtin_amdgcn_exp2f(a[2]), __builtin_amdgcn_exp2f(a[3]) };
    f32x2 em01 = __builtin_elementwise_fma(e01, L2, nL2);   // v_pk_fma_f32
    f32x2 em23 = __builtin_elementwise_fma(e23, L2, nL2);
    s16x4 r;
    r[0] = bfb(__builtin_amdgcn_fmed3f(a[0], em01.x, 0.0f));
    r[1] = bfb(__builtin_amdgcn_fmed3f(a[1], em01.y, 0.0f));
    r[2] = bfb(__builtin_amdgcn_fmed3f(a[2], em23.x, 0.0f));
    r[3] = bfb(__builtin_amdgcn_fmed3f(a[3], em23.y, 0.0f));
    return r;
}

#define MFMA16(A, B, C) __builtin_amdgcn_mfma_f32_16x16x16bf16_1k((A), (B), (C), 0, 0, 0)
#define SCHED_WALL()    __builtin_amdgcn_sched_barrier(0)

// Block = one feature f x 1024 rows; 4 waves x 64 rows per 256-row tile.
// HISTORY (do not regress):
//   R1 (256,4) 4-n chains, no walls  -> SPILL (FETCH 470MB)         274us
//   R2 (256,4) 2-half, no walls      -> SPILL (FETCH 460MB)         248us
//   R3 (256,3) 4-n chains, no walls  -> STILL SPILLS (FETCH 254MB)  176us
//   R4 (256,3) 4-n + sched_barrier(0) WALLS -> NO SPILL             108.7us
//   R5 log2-celu via __builtin_exp2f -> denormal-fixup bloat        144us REGRESS
//   R6 raw __builtin_amdgcn_exp2f    -> VALU-issue-bound            92.8us
//     (VALUBusy 77, Mfma 35, Occ 35% = 3 blk/CU, FETCH 35MB WRITE 64MB)
//   R7 2-half + walls at (256,4)     -> MILD SPILL (WRITE 90MB) +
//     doubled bank conflicts; occupancy gain eaten                  98.6us REGRESS
//     => occupancy lever is DEAD; (256,3) is the operating point.
//   R8 (this): R6 + packed-f32 fma (elementwise_fma on f32x2) for the em step
//     and the epilogue dot -> fewer VALU issue slots, same math.
// Spill tripwire: FETCH >> 40MB / WRITE >> 70MB -> revert to R6.
__global__ __launch_bounds__(NT, 3) void mlp64(
    const float* __restrict__ x,      // [B,F]
    const float* __restrict__ w_in,
    const float* __restrict__ b_in,
    const float* __restrict__ w_hid,
    const float* __restrict__ b_hid,
    const float* __restrict__ w_out,
    const float* __restrict__ b_out,
    float* __restrict__ out,          // [B,F]
    int Btot)
{
    const int f    = blockIdx.x & (F - 1);
    const int blk  = blockIdx.x >> 6;
    const int row0 = blk * ROWS_PER_BLOCK;
    const int t    = threadIdx.x;
    const int lane = t & 63;
    const int l15  = lane & 15;
    const int q    = lane >> 4;
    const int wrow = (t >> 6) * 64;   // 64-row wave-private slice

    __shared__ __align__(16) bf16  wlds[2][H][WPAD];   // hidden weights [layer][out][in], 18.4 KB
    __shared__ __align__(16) float s_bias[3][H];       // pre-scaled by log2e
    __shared__ __align__(16) float s_wout[H];          // pre-scaled by ln2

    // ---- stage both hidden layers' weights into LDS (fp32 -> bf16, once per block) ----
    for (int idx = t; idx < 1024; idx += NT) {
        const int l   = idx >> 9;
        const int row = (idx >> 3) & 63;
        const int ch  = idx & 7;
        const float* p = w_hid + (((size_t)l * F + f) << 12) + (row << 6) + (ch << 3);
        float4 a = *(const float4*)p, b = *(const float4*)(p + 4);
        bf16x8 v;
        v[0] = (bf16)a.x; v[1] = (bf16)a.y; v[2] = (bf16)a.z; v[3] = (bf16)a.w;
        v[4] = (bf16)b.x; v[5] = (bf16)b.y; v[6] = (bf16)b.z; v[7] = (bf16)b.w;
        *(bf16x8*)&wlds[l][row][ch * 8] = v;
    }
    if (t < H)           s_bias[0][t]         = b_in[f * H + t] * LOG2E;
    else if (t < 2 * H)  s_bias[1][t - H]     = b_hid[(0 * F + f) * H + (t - H)] * LOG2E;
    else if (t < 3 * H)  s_bias[2][t - 2 * H] = b_hid[(1 * F + f) * H + (t - 2 * H)] * LOG2E;
    else                 s_wout[t - 3 * H]    = w_out[f * H + (t - 3 * H)] * LN2;
    __syncthreads();

    // ---- layer-in A frags (log2e-scaled): quad 0 holds (w_hi, w_lo, w_hi, 0) ----
    s16x4 A1[4];
    #pragma unroll
    for (int m = 0; m < 4; ++m) {
        float w  = w_in[f * H + m * 16 + l15] * LOG2E;
        bf16 hb  = (bf16)w;
        short hi = __builtin_bit_cast(short, hb);
        short lo = bfb(w - (float)hb);
        s16x4 v  = {};
        if (q == 0) { v[0] = hi; v[1] = lo; v[2] = hi; }
        A1[m] = v;
    }

    const float bo = b_out[f];

    // strided 4B x loads; sharers are temporally adjacent blocks -> L2 hits
    float xc[4], xn[4];
    #pragma unroll
    for (int n = 0; n < 4; ++n)
        xc[n] = x[(size_t)(row0 + wrow + n * 16 + l15) * F + f];

    #pragma unroll 1
    for (int it = 0; it < ITERS; ++it) {
        const int rbase = row0 + it * TILE_ROWS + wrow;

        // B1 frags: quad 0 holds (x_hi, x_hi, x_lo, 0) in k-slots 0..3
        s16x4 B1[4];
        #pragma unroll
        for (int n = 0; n < 4; ++n) {
            bf16 hb  = (bf16)xc[n];
            short hh = __builtin_bit_cast(short, hb);
            short ll = bfb(xc[n] - (float)hb);
            s16x4 v  = {};
            if (q == 0) { v[0] = hh; v[1] = hh; v[2] = ll; }
            B1[n] = v;
        }
        #pragma unroll
        for (int n = 0; n < 4; ++n)
            xn[n] = (it + 1 < ITERS)
                  ? x[(size_t)(rbase + TILE_ROWS + n * 16 + l15) * F + f] : 0.0f;

        // ---- layer in->H: one K=16 MFMA per (m,n), D-frag -> B-frag of hidden-0 ----
        s16x4 Bh[4][4];                       // [n][kf]
        #pragma unroll
        for (int m = 0; m < 4; ++m) {
            f32x4 c0 = *(const f32x4*)&s_bias[0][m * 16 + q * 4];
            f32x4 a[4];
            #pragma unroll
            for (int n = 0; n < 4; ++n)
                a[n] = MFMA16(A1[m], B1[n], c0);
            #pragma unroll
            for (int n = 0; n < 4; ++n)
                Bh[n][m] = celu_frag(a[n]);
        }

        SCHED_WALL();   // keep hidden-0's ds_reads/live-ranges out of layer-in

        // ---- hidden layer 0 (LDS weight frags, K=16 chain of 4) ----
        s16x4 Bh2[4][4];
        #pragma unroll
        for (int m = 0; m < 4; ++m) {
            s16x4 Aw[4];
            #pragma unroll
            for (int kf = 0; kf < 4; ++kf)
                Aw[kf] = *(const s16x4*)&wlds[0][m * 16 + l15][kf * 16 + q * 4];
            f32x4 c0 = *(const f32x4*)&s_bias[1][m * 16 + q * 4];
            f32x4 a[4];
            #pragma unroll
            for (int n = 0; n < 4; ++n) {
                f32x4 acc = MFMA16(Aw[0], Bh[n][0], c0);
                acc = MFMA16(Aw[1], Bh[n][1], acc);
                acc = MFMA16(Aw[2], Bh[n][2], acc);
                acc = MFMA16(Aw[3], Bh[n][3], acc);
                a[n] = acc;
            }
            #pragma unroll
            for (int n = 0; n < 4; ++n)
                Bh2[n][m] = celu_frag(a[n]);
        }

        SCHED_WALL();   // keep hidden-1's ds_reads/live-ranges out of hidden-0

        // ---- hidden layer 1 + output dot in registers (packed-f32 dot) ----
        {
            const f32x2 L2  = {  LOG2E,  LOG2E };
            const f32x2 nL2 = { -LOG2E, -LOG2E };
            f32x2 sv[4] = { {0.0f, 0.0f}, {0.0f, 0.0f}, {0.0f, 0.0f}, {0.0f, 0.0f} };
            #pragma unroll
            for (int m = 0; m < 4; ++m) {
                s16x4 Aw[4];
                #pragma unroll
                for (int kf = 0; kf < 4; ++kf)
                    Aw[kf] = *(const s16x4*)&wlds[1][m * 16 + l15][kf * 16 + q * 4];
                f32x4 c0 = *(const f32x4*)&s_bias[2][m * 16 + q * 4];
                f32x2 wo01 = *(const f32x2*)&s_wout[m * 16 + q * 4];
                f32x2 wo23 = *(const f32x2*)&s_wout[m * 16 + q * 4 + 2];
                f32x4 a[4];
                #pragma unroll
                for (int n = 0; n < 4; ++n) {
                    f32x4 acc = MFMA16(Aw[0], Bh2[n][0], c0);
                    acc = MFMA16(Aw[1], Bh2[n][1], acc);
                    acc = MFMA16(Aw[2], Bh2[n][2], acc);
                    acc = MFMA16(Aw[3], Bh2[n][3], acc);
                    a[n] = acc;
                }
                #pragma unroll
                for (int n = 0; n < 4; ++n) {
                    f32x2 e01 = { __builtin_amdgcn_exp2f(a[n][0]), __builtin_amdgcn_exp2f(a[n][1]) };
                    f32x2 e23 = { __builtin_amdgcn_exp2f(a[n][2]), __builtin_amdgcn_exp2f(a[n][3]) };
                    f32x2 em01 = __builtin_elementwise_fma(e01, L2, nL2);
                    f32x2 em23 = __builtin_elementwise_fma(e23, L2, nL2);
                    f32x2 z01 = { __builtin_amdgcn_fmed3f(a[n][0], em01.x, 0.0f),
                                  __builtin_amdgcn_fmed3f(a[n][1], em01.y, 0.0f) };
                    f32x2 z23 = { __builtin_amdgcn_fmed3f(a[n][2], em23.x, 0.0f),
                                  __builtin_amdgcn_fmed3f(a[n][3], em23.y, 0.0f) };
                    sv[n] = __builtin_elementwise_fma(z01, wo01, sv[n]);
                    sv[n] = __builtin_elementwise_fma(z23, wo23, sv[n]);
                }
            }
            float s[4];
            #pragma unroll
            for (int n = 0; n < 4; ++n) {
                s[n] = sv[n].x + sv[n].y;
                s[n] += __shfl_xor(s[n], 16, 64);
                s[n] += __shfl_xor(s[n], 32, 64);
            }
            if (q == 0) {
                #pragma unroll
                for (int n = 0; n < 4; ++n)
                    out[(size_t)(rbase + n * 16 + l15) * F + f] = s[n] + bo;
            }
        }

        SCHED_WALL();   // keep next iteration's work out of this one's epilogue

        #pragma unroll
        for (int n = 0; n < 4; ++n) xc[n] = xn[n];
    }
}

extern "C" void kernel_launch(void* const* d_in, const int* in_sizes, int n_in,
                              void* d_out, int out_size, void* d_ws, size_t ws_size,
                              hipStream_t stream) {
    const float* x     = (const float*)d_in[0];
    const float* w_in  = (const float*)d_in[1];
    const float* b_in  = (const float*)d_in[2];
    const float* w_hid = (const float*)d_in[3];
    const float* b_hid = (const float*)d_in[4];
    const float* w_out = (const float*)d_in[5];
    const float* b_out = (const float*)d_in[6];
    float* out = (float*)d_out;

    const int Btot = in_sizes[0] / F;                       // 32768
    dim3 grid((unsigned)((Btot / ROWS_PER_BLOCK) * F));     // 2048 blocks
    dim3 block(NT);
    mlp64<<<grid, block, 0, stream>>>(x, w_in, b_in, w_hid, b_hid, w_out, b_out, out, Btot);
}

// Round 10
// 148.344 us; speedup vs baseline: 1.0410x; 1.0410x over previous
//
#include <hip/hip_runtime.h>

#define F 64
#define H 64
#define NT 256
#define TILE_ROWS 256     // per block per iteration: 4 waves x 64 rows
#define ITERS 4
#define ROWS_PER_BLOCK (TILE_ROWS * ITERS)   // 1024

#define LOG2E 1.44269504088896340736f
#define LN2   0.69314718055994530942f

typedef __bf16 bf16;
typedef __attribute__((ext_vector_type(4))) __bf16 bf16x4;
typedef __attribute__((ext_vector_type(4))) short s16x4;   // v4i16: one 16x16x16 bf16 A/B frag
typedef __attribute__((ext_vector_type(8))) short s16x8;   // two frags (one b128)
typedef __attribute__((ext_vector_type(4))) float f32x4;

// LOG2-DOMAIN CELU (R6, verified): activations carry a log2(e) scale end-to-end.
//   y = log2e * x ;  z = log2e * celu(x) = med3(y, log2e*exp2(y) - log2e, 0)
// MUST use raw __builtin_amdgcn_exp2f (bare v_exp_f32): the std __builtin_exp2f
// emits a denormal-range fixup (+40% VALU, R5 regression). Raw exp2's
// flush-to-zero for y<-126 is exactly right here (em -> -log2e -> output -1).
// Scale bookkeeping: w_in,b_in,b_hid pre-scaled by log2e at staging; hidden W
// UNCHANGED (scale passes through: W*(z*ln2)*log2e = W*z); w_out by ln2.
// R8 POST-MORTEM: do NOT pack these into f32x2 pk_fma -- pairing adds v_movs
// and serializes the 4 independent chains (VALU busy -8% but time +8%).
__device__ __forceinline__ float celu_l2(float y) {
    float em = fmaf(LOG2E, __builtin_amdgcn_exp2f(y), -LOG2E);
    return __builtin_amdgcn_fmed3f(y, em, 0.0f);
}

__device__ __forceinline__ short bfb(float v) {
    bf16 h = (bf16)v;
    return __builtin_bit_cast(short, h);
}

// post-layer activation: log2-domain celu on the 4 accum lanes, pack to a v4i16
// bf16 frag. KEY INVARIANT: for v_mfma_f32_16x16x16_bf16 the D layout
// (col=lane&15, row=(lane>>4)*4+j) is IDENTICAL to the B layout, so this frag
// is directly the next layer's B operand (kf = current m). No LDS round-trip.
__device__ __forceinline__ s16x4 celu_frag(f32x4 a) {
    s16x4 r;
    r[0] = bfb(celu_l2(a[0]));
    r[1] = bfb(celu_l2(a[1]));
    r[2] = bfb(celu_l2(a[2]));
    r[3] = bfb(celu_l2(a[3]));
    return r;
}

#define MFMA16(A, B, C) __builtin_amdgcn_mfma_f32_16x16x16bf16_1k((A), (B), (C), 0, 0, 0)
#define SCHED_WALL()    __builtin_amdgcn_sched_barrier(0)

// R9 WEIGHT LDS LAYOUT (fragment-order + XOR swizzle), replaces WPAD rows:
//   wlds[l][row][64] -- 128B rows, no pad. Element k = kf*16 + q*4 + j of row r
//   is stored at col' = q*16 + kf*4 + j, then the 16B unit index u = 2q+(kf>>1)
//   is XOR-swizzled by (r&7):  elem = r*64 + (u ^ (r&7))*8 + (kf&1)*4.
//   Lane (l15,q) reads its 4 frags as TWO ds_read_b128 (h=0,1) at
//   u_r = (2q+h) ^ (l15&7): unit contains kf=2h (sub 0) and kf=2h+1 (sub 8B)
//   for that lane's q. Banks: per instr, (2q+h)^(l15&7) spreads 64 lanes
//   exactly 8 per 16B slot = the 1KB-read hardware minimum -> conflict-free
//   (R6's b64 reads were 4.19M conflict cycles = ~4 extra cyc per read), and
//   LDS instrs halve (128 -> 64 per wave).
// R9 bench attempt failed with "MI355X container failed twice" = infra error
// (no compile/validation failure); layout re-audited (bijective staging, 16B-
// aligned reads, in-bounds) -> resubmitted unchanged.
// HISTORY (do not regress):
//   R1 (256,4) 4-n chains, no walls  -> SPILL (FETCH 470MB)         274us
//   R2 (256,4) 2-half, no walls      -> SPILL (FETCH 460MB)         248us
//   R3 (256,3) 4-n chains, no walls  -> STILL SPILLS (FETCH 254MB)  176us
//   R4 (256,3) 4-n + sched_barrier(0) WALLS -> NO SPILL             108.7us
//   R5 log2-celu via __builtin_exp2f -> denormal-fixup bloat        144us REGRESS
//   R6 raw __builtin_amdgcn_exp2f    -> VALU-issue-bound            92.8us
//   R7 2-half + walls at (256,4)     -> MILD SPILL + 2x conflicts   98.6us REGRESS
//   R8 packed-f32 fma (pk pairs)     -> dep-serialization           100us REGRESS
//   R9 (this): R6 + conflict-free b128 weight reads (layout above).
// Spill tripwire: FETCH >> 40MB / WRITE >> 70MB -> revert to R6.
__global__ __launch_bounds__(NT, 3) void mlp64(
    const float* __restrict__ x,      // [B,F]
    const float* __restrict__ w_in,
    const float* __restrict__ b_in,
    const float* __restrict__ w_hid,
    const float* __restrict__ b_hid,
    const float* __restrict__ w_out,
    const float* __restrict__ b_out,
    float* __restrict__ out,          // [B,F]
    int Btot)
{
    const int f    = blockIdx.x & (F - 1);
    const int blk  = blockIdx.x >> 6;
    const int row0 = blk * ROWS_PER_BLOCK;
    const int t    = threadIdx.x;
    const int lane = t & 63;
    const int l15  = lane & 15;
    const int q    = lane >> 4;
    const int wrow = (t >> 6) * 64;   // 64-row wave-private slice
    const int t7   = l15 & 7;         // xor key for swizzled weight reads

    __shared__ __align__(16) bf16  wlds[2][H][64];     // 16 KB, fragment-order + xor layout
    __shared__ __align__(16) float s_bias[3][H];       // pre-scaled by log2e
    __shared__ __align__(16) float s_wout[H];          // pre-scaled by ln2

    // ---- stage both hidden layers' weights into LDS (fp32 -> bf16, once per block) ----
    // Each thread handles one (l, row, ch): 8 consecutive fp32 of W[row][ch*8..].
    // k = ch*8+i -> kf = ch>>1 (same for all 8), q = (2ch + (i>>2)) & 3, j = i&3.
    // Two 4-elem chunks land at swizzled units (see layout comment above).
    for (int idx = t; idx < 1024; idx += NT) {
        const int l   = idx >> 9;
        const int row = (idx >> 3) & 63;
        const int ch  = idx & 7;
        const int kf  = ch >> 1;
        const float* p = w_hid + (((size_t)l * F + f) << 12) + (row << 6) + (ch << 3);
        float4 a = *(const float4*)p, b = *(const float4*)(p + 4);
        const int rx   = row & 7;
        const int q1   = (2 * ch) & 3;
        const int q2   = (2 * ch + 1) & 3;
        const int sub  = (kf & 1) * 4;            // elems
        const int hi   = kf >> 1;
        bf16x4 c1, c2;
        c1[0] = (bf16)a.x; c1[1] = (bf16)a.y; c1[2] = (bf16)a.z; c1[3] = (bf16)a.w;
        c2[0] = (bf16)b.x; c2[1] = (bf16)b.y; c2[2] = (bf16)b.z; c2[3] = (bf16)b.w;
        *(bf16x4*)&wlds[l][row][((2 * q1 + hi) ^ rx) * 8 + sub] = c1;
        *(bf16x4*)&wlds[l][row][((2 * q2 + hi) ^ rx) * 8 + sub] = c2;
    }
    if (t < H)           s_bias[0][t]         = b_in[f * H + t] * LOG2E;
    else if (t < 2 * H)  s_bias[1][t - H]     = b_hid[(0 * F + f) * H + (t - H)] * LOG2E;
    else if (t < 3 * H)  s_bias[2][t - 2 * H] = b_hid[(1 * F + f) * H + (t - 2 * H)] * LOG2E;
    else                 s_wout[t - 3 * H]    = w_out[f * H + (t - 3 * H)] * LN2;
    __syncthreads();

    // ---- layer-in A frags (log2e-scaled): quad 0 holds (w_hi, w_lo, w_hi, 0) ----
    s16x4 A1[4];
    #pragma unroll
    for (int m = 0; m < 4; ++m) {
        float w  = w_in[f * H + m * 16 + l15] * LOG2E;
        bf16 hb  = (bf16)w;
        short hi = __builtin_bit_cast(short, hb);
        short lo = bfb(w - (float)hb);
        s16x4 v  = {};
        if (q == 0) { v[0] = hi; v[1] = lo; v[2] = hi; }
        A1[m] = v;
    }

    const float bo = b_out[f];

    // strided 4B x loads; sharers are temporally adjacent blocks -> L2 hits
    float xc[4], xn[4];
    #pragma unroll
    for (int n = 0; n < 4; ++n)
        xc[n] = x[(size_t)(row0 + wrow + n * 16 + l15) * F + f];

    const int u0 = (2 * q) ^ t7;      // swizzled unit for h=0 (h=1 is u0^1)

    #pragma unroll 1
    for (int it = 0; it < ITERS; ++it) {
        const int rbase = row0 + it * TILE_ROWS + wrow;

        // B1 frags: quad 0 holds (x_hi, x_hi, x_lo, 0) in k-slots 0..3
        s16x4 B1[4];
        #pragma unroll
        for (int n = 0; n < 4; ++n) {
            bf16 hb  = (bf16)xc[n];
            short hh = __builtin_bit_cast(short, hb);
            short ll = bfb(xc[n] - (float)hb);
            s16x4 v  = {};
            if (q == 0) { v[0] = hh; v[1] = hh; v[2] = ll; }
            B1[n] = v;
        }
        #pragma unroll
        for (int n = 0; n < 4; ++n)
            xn[n] = (it + 1 < ITERS)
                  ? x[(size_t)(rbase + TILE_ROWS + n * 16 + l15) * F + f] : 0.0f;

        // ---- layer in->H: one K=16 MFMA per (m,n), D-frag -> B-frag of hidden-0 ----
        s16x4 Bh[4][4];                       // [n][kf]
        #pragma unroll
        for (int m = 0; m < 4; ++m) {
            f32x4 c0 = *(const f32x4*)&s_bias[0][m * 16 + q * 4];
            f32x4 a[4];
            #pragma unroll
            for (int n = 0; n < 4; ++n)
                a[n] = MFMA16(A1[m], B1[n], c0);
            #pragma unroll
            for (int n = 0; n < 4; ++n)
                Bh[n][m] = celu_frag(a[n]);
        }

        SCHED_WALL();   // keep hidden-0's ds_reads/live-ranges out of layer-in

        // ---- hidden layer 0 (swizzled b128 weight frags, K=16 chain of 4) ----
        s16x4 Bh2[4][4];
        #pragma unroll
        for (int m = 0; m < 4; ++m) {
            s16x8 w0 = *(const s16x8*)&wlds[0][m * 16 + l15][u0 * 8];
            s16x8 w1 = *(const s16x8*)&wlds[0][m * 16 + l15][(u0 ^ 1) * 8];
            s16x4 Aw[4];
            Aw[0] = s16x4{w0[0], w0[1], w0[2], w0[3]};
            Aw[1] = s16x4{w0[4], w0[5], w0[6], w0[7]};
            Aw[2] = s16x4{w1[0], w1[1], w1[2], w1[3]};
            Aw[3] = s16x4{w1[4], w1[5], w1[6], w1[7]};
            f32x4 c0 = *(const f32x4*)&s_bias[1][m * 16 + q * 4];
            f32x4 a[4];
            #pragma unroll
            for (int n = 0; n < 4; ++n) {
                f32x4 acc = MFMA16(Aw[0], Bh[n][0], c0);
                acc = MFMA16(Aw[1], Bh[n][1], acc);
                acc = MFMA16(Aw[2], Bh[n][2], acc);
                acc = MFMA16(Aw[3], Bh[n][3], acc);
                a[n] = acc;
            }
            #pragma unroll
            for (int n = 0; n < 4; ++n)
                Bh2[n][m] = celu_frag(a[n]);
        }

        SCHED_WALL();   // keep hidden-1's ds_reads/live-ranges out of hidden-0

        // ---- hidden layer 1 + output dot in registers (no cvt on last layer) ----
        {
            float s[4] = {0.0f, 0.0f, 0.0f, 0.0f};
            #pragma unroll
            for (int m = 0; m < 4; ++m) {
                s16x8 w0 = *(const s16x8*)&wlds[1][m * 16 + l15][u0 * 8];
                s16x8 w1 = *(const s16x8*)&wlds[1][m * 16 + l15][(u0 ^ 1) * 8];
                s16x4 Aw[4];
                Aw[0] = s16x4{w0[0], w0[1], w0[2], w0[3]};
                Aw[1] = s16x4{w0[4], w0[5], w0[6], w0[7]};
                Aw[2] = s16x4{w1[0], w1[1], w1[2], w1[3]};
                Aw[3] = s16x4{w1[4], w1[5], w1[6], w1[7]};
                f32x4 c0 = *(const f32x4*)&s_bias[2][m * 16 + q * 4];
                f32x4 wo = *(const f32x4*)&s_wout[m * 16 + q * 4];
                f32x4 a[4];
                #pragma unroll
                for (int n = 0; n < 4; ++n) {
                    f32x4 acc = MFMA16(Aw[0], Bh2[n][0], c0);
                    acc = MFMA16(Aw[1], Bh2[n][1], acc);
                    acc = MFMA16(Aw[2], Bh2[n][2], acc);
                    acc = MFMA16(Aw[3], Bh2[n][3], acc);
                    a[n] = acc;
                }
                #pragma unroll
                for (int n = 0; n < 4; ++n)
                    #pragma unroll
                    for (int rr = 0; rr < 4; ++rr)
                        s[n] = fmaf(celu_l2(a[n][rr]), wo[rr], s[n]);
            }
            #pragma unroll
            for (int n = 0; n < 4; ++n) {
                s[n] += __shfl_xor(s[n], 16, 64);
                s[n] += __shfl_xor(s[n], 32, 64);
            }
            if (q == 0) {
                #pragma unroll
                for (int n = 0; n < 4; ++n)
                    out[(size_t)(rbase + n * 16 + l15) * F + f] = s[n] + bo;
            }
        }

        SCHED_WALL();   // keep next iteration's work out of this one's epilogue

        #pragma unroll
        for (int n = 0; n < 4; ++n) xc[n] = xn[n];
    }
}

extern "C" void kernel_launch(void* const* d_in, const int* in_sizes, int n_in,
                              void* d_out, int out_size, void* d_ws, size_t ws_size,
                              hipStream_t stream) {
    const float* x     = (const float*)d_in[0];
    const float* w_in  = (const float*)d_in[1];
    const float* b_in  = (const float*)d_in[2];
    const float* w_hid = (const float*)d_in[3];
    const float* b_hid = (const float*)d_in[4];
    const float* w_out = (const float*)d_in[5];
    const float* b_out = (const float*)d_in[6];
    float* out = (float*)d_out;

    const int Btot = in_sizes[0] / F;                       // 32768
    dim3 grid((unsigned)((Btot / ROWS_PER_BLOCK) * F));     // 2048 blocks
    dim3 block(NT);
    mlp64<<<grid, block, 0, stream>>>(x, w_in, b_in, w_hid, b_hid, w_out, b_out, out, Btot);
}

// Round 11
// 148.212 us; speedup vs baseline: 1.0419x; 1.0009x over previous
//
#include <hip/hip_runtime.h>

#define F 64
#define H 64
#define NT 256
#define TILE_ROWS 256     // per block per iteration: 4 waves x 64 rows
#define ITERS 4
#define ROWS_PER_BLOCK (TILE_ROWS * ITERS)   // 1024

#define LOG2E 1.44269504088896340736f
#define LN2   0.69314718055994530942f

typedef __bf16 bf16;
typedef __attribute__((ext_vector_type(4))) __bf16 bf16x4;
typedef __attribute__((ext_vector_type(4))) short s16x4;   // v4i16: one 16x16x16 bf16 A/B frag
typedef __attribute__((ext_vector_type(8))) short s16x8;   // two frags (one b128)
typedef __attribute__((ext_vector_type(4))) float f32x4;

// LOG2-DOMAIN CELU (R6, verified): activations carry a log2(e) scale end-to-end.
//   y = log2e * x ;  z = log2e * celu(x) = med3(y, log2e*exp2(y) - log2e, 0)
// MUST use raw __builtin_amdgcn_exp2f (bare v_exp_f32): the std __builtin_exp2f
// emits a denormal-range fixup (+40% VALU, R5 regression). Raw exp2's
// flush-to-zero for y<-126 is exactly right here (em -> -log2e -> output -1).
// Scale bookkeeping: w_in,b_in,b_hid pre-scaled by log2e at staging; hidden W
// UNCHANGED (scale passes through: W*(z*ln2)*log2e = W*z); w_out by ln2.
// R8 POST-MORTEM: do NOT pack these into f32x2 pk_fma -- pairing adds v_movs
// and serializes the 4 independent chains (VALU busy -8% but time +8%).
__device__ __forceinline__ float celu_l2(float y) {
    float em = fmaf(LOG2E, __builtin_amdgcn_exp2f(y), -LOG2E);
    return __builtin_amdgcn_fmed3f(y, em, 0.0f);
}

__device__ __forceinline__ short bfb(float v) {
    bf16 h = (bf16)v;
    return __builtin_bit_cast(short, h);
}

// post-layer activation: log2-domain celu on the 4 accum lanes, pack to a v4i16
// bf16 frag. KEY INVARIANT: for v_mfma_f32_16x16x16_bf16 the D layout
// (col=lane&15, row=(lane>>4)*4+j) is IDENTICAL to the B layout, so this frag
// is directly the next layer's B operand (kf = current m). No LDS round-trip.
__device__ __forceinline__ s16x4 celu_frag(f32x4 a) {
    s16x4 r;
    r[0] = bfb(celu_l2(a[0]));
    r[1] = bfb(celu_l2(a[1]));
    r[2] = bfb(celu_l2(a[2]));
    r[3] = bfb(celu_l2(a[3]));
    return r;
}

#define MFMA16(A, B, C) __builtin_amdgcn_mfma_f32_16x16x16bf16_1k((A), (B), (C), 0, 0, 0)
#define SCHED_WALL()    __builtin_amdgcn_sched_barrier(0)
// R11: inter-stage walls allow DS_READ (mask 0x100) to cross -- next stage's
// weight ds_read_b128s can issue under this stage's MFMA/celu stream (hides
// ~120cy lgkm first-use latency at each stage boundary), while VALU/MFMA
// reordering stays pinned (the R1-R3 spill driver was stacked COMPUTE live
// ranges, not the reads). Worst case +32 VGPRs across crossover: ~162 <= 170.
#define SCHED_WALL_DSPASS() __builtin_amdgcn_sched_barrier(0x100)

// R9/R10 WEIGHT LDS LAYOUT (fragment-order + XOR swizzle):
//   wlds[l][row][64] -- 128B rows, no pad. Element k = kf*16 + q*4 + j of row r
//   is stored at col' = q*16 + kf*4 + j, then the 16B unit index u = 2q+(kf>>1)
//   is XOR-swizzled by (r&7):  elem = r*64 + (u ^ (r&7))*8 + (kf&1)*4.
//   Lane (l15,q) reads its 4 frags as TWO ds_read_b128 (h=0,1) at
//   u_r = (2q+h) ^ (l15&7). R10 MEASURED: conflicts 4.19M -> 2.36M, LDS instrs
//   halved, dur NULL (92.8 -> 92.4-94.2): conflicts were off critical path at
//   3 waves/SIMD. Kept anyway (fewer issue slots, never worse).
// HISTORY (do not regress):
//   R1 (256,4) 4-n chains, no walls  -> SPILL (FETCH 470MB)         274us
//   R2 (256,4) 2-half, no walls      -> SPILL (FETCH 460MB)         248us
//   R3 (256,3) 4-n chains, no walls  -> STILL SPILLS (FETCH 254MB)  176us
//   R4 (256,3) 4-n + sched_barrier(0) WALLS -> NO SPILL             108.7us
//   R5 log2-celu via __builtin_exp2f -> denormal-fixup bloat        144us REGRESS
//   R6 raw __builtin_amdgcn_exp2f    -> VALU-issue-bound            92.8us
//   R7 2-half + walls at (256,4)     -> MILD SPILL + 2x conflicts   98.6us REGRESS
//   R8 packed-f32 fma (pk pairs)     -> dep-serialization           100us REGRESS
//   R9/R10 conflict-free b128 weight reads -> conflicts -44%, dur NULL  92.8us
//   R11 (this): DS_READ-permeable inter-stage walls (mask 0x100) -> attack the
//     22% issue-idle (lgkm waits at stage starts). Epilogue wall stays 0.
// Spill tripwire: FETCH >> 40MB / WRITE >> 70MB -> revert walls to mask 0.
__global__ __launch_bounds__(NT, 3) void mlp64(
    const float* __restrict__ x,      // [B,F]
    const float* __restrict__ w_in,
    const float* __restrict__ b_in,
    const float* __restrict__ w_hid,
    const float* __restrict__ b_hid,
    const float* __restrict__ w_out,
    const float* __restrict__ b_out,
    float* __restrict__ out,          // [B,F]
    int Btot)
{
    const int f    = blockIdx.x & (F - 1);
    const int blk  = blockIdx.x >> 6;
    const int row0 = blk * ROWS_PER_BLOCK;
    const int t    = threadIdx.x;
    const int lane = t & 63;
    const int l15  = lane & 15;
    const int q    = lane >> 4;
    const int wrow = (t >> 6) * 64;   // 64-row wave-private slice
    const int t7   = l15 & 7;         // xor key for swizzled weight reads

    __shared__ __align__(16) bf16  wlds[2][H][64];     // 16 KB, fragment-order + xor layout
    __shared__ __align__(16) float s_bias[3][H];       // pre-scaled by log2e
    __shared__ __align__(16) float s_wout[H];          // pre-scaled by ln2

    // ---- stage both hidden layers' weights into LDS (fp32 -> bf16, once per block) ----
    for (int idx = t; idx < 1024; idx += NT) {
        const int l   = idx >> 9;
        const int row = (idx >> 3) & 63;
        const int ch  = idx & 7;
        const int kf  = ch >> 1;
        const float* p = w_hid + (((size_t)l * F + f) << 12) + (row << 6) + (ch << 3);
        float4 a = *(const float4*)p, b = *(const float4*)(p + 4);
        const int rx   = row & 7;
        const int q1   = (2 * ch) & 3;
        const int q2   = (2 * ch + 1) & 3;
        const int sub  = (kf & 1) * 4;            // elems
        const int hi   = kf >> 1;
        bf16x4 c1, c2;
        c1[0] = (bf16)a.x; c1[1] = (bf16)a.y; c1[2] = (bf16)a.z; c1[3] = (bf16)a.w;
        c2[0] = (bf16)b.x; c2[1] = (bf16)b.y; c2[2] = (bf16)b.z; c2[3] = (bf16)b.w;
        *(bf16x4*)&wlds[l][row][((2 * q1 + hi) ^ rx) * 8 + sub] = c1;
        *(bf16x4*)&wlds[l][row][((2 * q2 + hi) ^ rx) * 8 + sub] = c2;
    }
    if (t < H)           s_bias[0][t]         = b_in[f * H + t] * LOG2E;
    else if (t < 2 * H)  s_bias[1][t - H]     = b_hid[(0 * F + f) * H + (t - H)] * LOG2E;
    else if (t < 3 * H)  s_bias[2][t - 2 * H] = b_hid[(1 * F + f) * H + (t - 2 * H)] * LOG2E;
    else                 s_wout[t - 3 * H]    = w_out[f * H + (t - 3 * H)] * LN2;
    __syncthreads();

    // ---- layer-in A frags (log2e-scaled): quad 0 holds (w_hi, w_lo, w_hi, 0) ----
    s16x4 A1[4];
    #pragma unroll
    for (int m = 0; m < 4; ++m) {
        float w  = w_in[f * H + m * 16 + l15] * LOG2E;
        bf16 hb  = (bf16)w;
        short hi = __builtin_bit_cast(short, hb);
        short lo = bfb(w - (float)hb);
        s16x4 v  = {};
        if (q == 0) { v[0] = hi; v[1] = lo; v[2] = hi; }
        A1[m] = v;
    }

    const float bo = b_out[f];

    // strided 4B x loads; sharers are temporally adjacent blocks -> L2 hits
    float xc[4], xn[4];
    #pragma unroll
    for (int n = 0; n < 4; ++n)
        xc[n] = x[(size_t)(row0 + wrow + n * 16 + l15) * F + f];

    const int u0 = (2 * q) ^ t7;      // swizzled unit for h=0 (h=1 is u0^1)

    #pragma unroll 1
    for (int it = 0; it < ITERS; ++it) {
        const int rbase = row0 + it * TILE_ROWS + wrow;

        // B1 frags: quad 0 holds (x_hi, x_hi, x_lo, 0) in k-slots 0..3
        s16x4 B1[4];
        #pragma unroll
        for (int n = 0; n < 4; ++n) {
            bf16 hb  = (bf16)xc[n];
            short hh = __builtin_bit_cast(short, hb);
            short ll = bfb(xc[n] - (float)hb);
            s16x4 v  = {};
            if (q == 0) { v[0] = hh; v[1] = hh; v[2] = ll; }
            B1[n] = v;
        }
        #pragma unroll
        for (int n = 0; n < 4; ++n)
            xn[n] = (it + 1 < ITERS)
                  ? x[(size_t)(rbase + TILE_ROWS + n * 16 + l15) * F + f] : 0.0f;

        // ---- layer in->H: one K=16 MFMA per (m,n), D-frag -> B-frag of hidden-0 ----
        s16x4 Bh[4][4];                       // [n][kf]
        #pragma unroll
        for (int m = 0; m < 4; ++m) {
            f32x4 c0 = *(const f32x4*)&s_bias[0][m * 16 + q * 4];
            f32x4 a[4];
            #pragma unroll
            for (int n = 0; n < 4; ++n)
                a[n] = MFMA16(A1[m], B1[n], c0);
            #pragma unroll
            for (int n = 0; n < 4; ++n)
                Bh[n][m] = celu_frag(a[n]);
        }

        SCHED_WALL_DSPASS();   // compute pinned; hidden-0's ds_reads may hoist

        // ---- hidden layer 0 (swizzled b128 weight frags, K=16 chain of 4) ----
        s16x4 Bh2[4][4];
        #pragma unroll
        for (int m = 0; m < 4; ++m) {
            s16x8 w0 = *(const s16x8*)&wlds[0][m * 16 + l15][u0 * 8];
            s16x8 w1 = *(const s16x8*)&wlds[0][m * 16 + l15][(u0 ^ 1) * 8];
            s16x4 Aw[4];
            Aw[0] = s16x4{w0[0], w0[1], w0[2], w0[3]};
            Aw[1] = s16x4{w0[4], w0[5], w0[6], w0[7]};
            Aw[2] = s16x4{w1[0], w1[1], w1[2], w1[3]};
            Aw[3] = s16x4{w1[4], w1[5], w1[6], w1[7]};
            f32x4 c0 = *(const f32x4*)&s_bias[1][m * 16 + q * 4];
            f32x4 a[4];
            #pragma unroll
            for (int n = 0; n < 4; ++n) {
                f32x4 acc = MFMA16(Aw[0], Bh[n][0], c0);
                acc = MFMA16(Aw[1], Bh[n][1], acc);
                acc = MFMA16(Aw[2], Bh[n][2], acc);
                acc = MFMA16(Aw[3], Bh[n][3], acc);
                a[n] = acc;
            }
            #pragma unroll
            for (int n = 0; n < 4; ++n)
                Bh2[n][m] = celu_frag(a[n]);
        }

        SCHED_WALL_DSPASS();   // compute pinned; hidden-1's ds_reads may hoist

        // ---- hidden layer 1 + output dot in registers (no cvt on last layer) ----
        {
            float s[4] = {0.0f, 0.0f, 0.0f, 0.0f};
            #pragma unroll
            for (int m = 0; m < 4; ++m) {
                s16x8 w0 = *(const s16x8*)&wlds[1][m * 16 + l15][u0 * 8];
                s16x8 w1 = *(const s16x8*)&wlds[1][m * 16 + l15][(u0 ^ 1) * 8];
                s16x4 Aw[4];
                Aw[0] = s16x4{w0[0], w0[1], w0[2], w0[3]};
                Aw[1] = s16x4{w0[4], w0[5], w0[6], w0[7]};
                Aw[2] = s16x4{w1[0], w1[1], w1[2], w1[3]};
                Aw[3] = s16x4{w1[4], w1[5], w1[6], w1[7]};
                f32x4 c0 = *(const f32x4*)&s_bias[2][m * 16 + q * 4];
                f32x4 wo = *(const f32x4*)&s_wout[m * 16 + q * 4];
                f32x4 a[4];
                #pragma unroll
                for (int n = 0; n < 4; ++n) {
                    f32x4 acc = MFMA16(Aw[0], Bh2[n][0], c0);
                    acc = MFMA16(Aw[1], Bh2[n][1], acc);
                    acc = MFMA16(Aw[2], Bh2[n][2], acc);
                    acc = MFMA16(Aw[3], Bh2[n][3], acc);
                    a[n] = acc;
                }
                #pragma unroll
                for (int n = 0; n < 4; ++n)
                    #pragma unroll
                    for (int rr = 0; rr < 4; ++rr)
                        s[n] = fmaf(celu_l2(a[n][rr]), wo[rr], s[n]);
            }
            #pragma unroll
            for (int n = 0; n < 4; ++n) {
                s[n] += __shfl_xor(s[n], 16, 64);
                s[n] += __shfl_xor(s[n], 32, 64);
            }
            if (q == 0) {
                #pragma unroll
                for (int n = 0; n < 4; ++n)
                    out[(size_t)(rbase + n * 16 + l15) * F + f] = s[n] + bo;
            }
        }

        SCHED_WALL();   // full wall: keep next iteration's work out of the epilogue

        #pragma unroll
        for (int n = 0; n < 4; ++n) xc[n] = xn[n];
    }
}

extern "C" void kernel_launch(void* const* d_in, const int* in_sizes, int n_in,
                              void* d_out, int out_size, void* d_ws, size_t ws_size,
                              hipStream_t stream) {
    const float* x     = (const float*)d_in[0];
    const float* w_in  = (const float*)d_in[1];
    const float* b_in  = (const float*)d_in[2];
    const float* w_hid = (const float*)d_in[3];
    const float* b_hid = (const float*)d_in[4];
    const float* w_out = (const float*)d_in[5];
    const float* b_out = (const float*)d_in[6];
    float* out = (float*)d_out;

    const int Btot = in_sizes[0] / F;                       // 32768
    dim3 grid((unsigned)((Btot / ROWS_PER_BLOCK) * F));     // 2048 blocks
    dim3 block(NT);
    mlp64<<<grid, block, 0, stream>>>(x, w_in, b_in, w_hid, b_hid, w_out, b_out, out, Btot);
}